// Round 5
// baseline (85.110 us; speedup 1.0000x reference)
//
#include <hip/hip_runtime.h>
#include <hip/hip_bf16.h>
#include <math.h>

// signs c1,c2 decoded in round 0/1: both +1 (absmax 0.0078 = bf16 noise)
#define C1 1.0f
#define C2 1.0f

static constexpr float EPSF = 1e-8f;
static constexpr int NIN = 1024;
static constexpr int NH  = 2048;
static constexpr int NU  = NIN + NH + 1;   // 3073

typedef __attribute__((ext_vector_type(8))) short bf16x8;
typedef __attribute__((ext_vector_type(4))) float f32x4;

// ws layout (bytes) -- MUST stay <= 16809984 (round-1 proven ws budget):
//   0       dh    2048 f32 (8 KiB)
//   8192    dhp   8 f32
//   8256    gp    512 f32 (2 KiB)
//   10304   nrm   3 f32
//   10320   coef  4 f32
//   16384   Abf   2048*2048 bf16 (8 MiB) = dh[m]*W_h[m][k]
//   8404992 Bt    2048*2048 bf16 (8 MiB) = A_prev^T
//   end 16793600
// z-partials (32*2048 f32, 256 KiB) live in d_out's Hq region (dead until k_gemm).

__device__ inline unsigned short f2bf(float f) {
  union { float f; unsigned u; } v; v.f = f;
  unsigned r = v.u + 0x7FFFu + ((v.u >> 16) & 1u);   // RNE
  return (unsigned short)(r >> 16);
}

__device__ inline float blockReduce256(float v, float* red) {
  int t = threadIdx.x;
  red[t] = v;
  __syncthreads();
  for (int s = 128; s > 0; s >>= 1) {
    if (t < s) red[t] += red[t + s];
    __syncthreads();
  }
  float r = red[0];
  __syncthreads();
  return r;
}

// z partials: 8 j-blocks x 32 i-slices (96 rows each) -> part[bi][j]. No atomics.
__global__ void k_z1(const float* __restrict__ x, const float* __restrict__ hprev,
                     const float* __restrict__ Win, const float* __restrict__ Wh,
                     float* __restrict__ part) {
  int b = blockIdx.x;
  int bj = b & 7, bi = b >> 3;
  int j = bj * 256 + threadIdx.x;
  int i0 = bi * 96, i1 = i0 + 96;       // 32*96 == 3072 == NIN+NH exactly
  float s = 0.f;
  for (int i = i0; i < i1; ++i) {
    if (i < NIN) s += x[i] * Win[(size_t)i * NH + j];
    else         s += hprev[i - NIN] * Wh[(size_t)(i - NIN) * NH + j];
  }
  part[bi * NH + j] = s;
}

__global__ void k_z2(const float* __restrict__ part, const float* __restrict__ bias,
                     float* __restrict__ outh, float* __restrict__ dh,
                     float* __restrict__ dhp) {
  __shared__ float red[256];
  int j = blockIdx.x * 256 + threadIdx.x;
  float z = bias[j];
  for (int bi = 0; bi < 32; ++bi) z += part[bi * NH + j];
  float h = tanhf(z);
  outh[j] = h;
  float d = 1.f - h * h;
  dh[j] = d;
  float s = blockReduce256(d * d, red);
  if (threadIdx.x == 0) dhp[blockIdx.x] = s;
}

// fused: blocks [0,4096) prep_a ; [4096,5120) prep_b ; 5120 norms
__global__ void k_prep(const float* __restrict__ Wh, const float* __restrict__ dh,
                       unsigned short* __restrict__ Abf,
                       const float* __restrict__ Ap, unsigned short* __restrict__ Bt,
                       const float* __restrict__ u, const float* __restrict__ x,
                       const float* __restrict__ hprev, float* __restrict__ nrm) {
  __shared__ float ls[64][65];
  int b = blockIdx.x;
  int t = threadIdx.x;
  if (b < 4096) {
    // Abf[m][k] = bf16(dh[m] * W_h[m][k]); 4096*256 float4 == 2^20 == Wh/4 exactly
    int idx4 = b * 256 + t;
    float4 w = ((const float4*)Wh)[idx4];
    float d = dh[idx4 >> 9];                    // 512 float4 per row
    ushort4 o;
    o.x = f2bf(w.x * d); o.y = f2bf(w.y * d);
    o.z = f2bf(w.z * d); o.w = f2bf(w.w * d);
    ((ushort4*)Abf)[idx4] = o;
  } else if (b < 5120) {
    // Bt[n][k] = bf16(A_prev[k][n]) -- 64x64 LDS-tiled transpose; 32x32 tiles
    int bb = b - 4096;
    int tn = bb & 31, tk = bb >> 5;
    int r = t >> 4, c = (t & 15) * 4;
#pragma unroll
    for (int i = 0; i < 4; ++i) {
      float4 v = *(const float4*)&Ap[(size_t)(tk * 64 + r + i * 16) * NH + tn * 64 + c];
      ls[r + i * 16][c] = v.x; ls[r + i * 16][c + 1] = v.y;
      ls[r + i * 16][c + 2] = v.z; ls[r + i * 16][c + 3] = v.w;
    }
    __syncthreads();
#pragma unroll
    for (int i = 0; i < 4; ++i) {
      int n = r + i * 16;
      ushort4 o;
      o.x = f2bf(ls[c][n]);     o.y = f2bf(ls[c + 1][n]);
      o.z = f2bf(ls[c + 2][n]); o.w = f2bf(ls[c + 3][n]);
      *(ushort4*)&Bt[(size_t)(tn * 64 + n) * NH + tk * 64 + c] = o;
    }
  } else {
    // norms: sumsq of u, x, h_prev
    float* red = (float*)ls;
    float su = 0, sx = 0, sh = 0;
    for (int i = t; i < NU;  i += 256) su += u[i] * u[i];
    for (int i = t; i < NIN; i += 256) sx += x[i] * x[i];
    for (int i = t; i < NH;  i += 256) sh += hprev[i] * hprev[i];
    float r0 = blockReduce256(su, red);
    float r1 = blockReduce256(sx, red);
    float r2 = blockReduce256(sh, red);
    if (t == 0) { nrm[0] = r0; nrm[1] = r1; nrm[2] = r2; }
  }
}

#define GLOAD_LDS(gsrc, ldst) \
  __builtin_amdgcn_global_load_lds( \
      (const __attribute__((address_space(1))) unsigned int*)(gsrc), \
      (__attribute__((address_space(3))) unsigned int*)(ldst), 16, 0, 0)

// C[m][n] = sum_k Abf[m][k]*Bt[n][k] (= H @ A_prev).
// 128x64 tile, BK=64, 4 waves; wave subtile 64x32 (acc[4][2]).
// Double-buffered LDS prefetch (T3 minimum 2-phase): stage tile t+1 BEFORE
// computing tile t so load latency hides under ds_read+MFMA; __syncthreads'
// implicit vmcnt(0) drain is the per-tile wait. 32 barriers (was 64).
// LDS kept as [2 kk][rows][32] halves: 64B row stride (8-way, not 16-way conflict).
// Grid 512 = 16 m-tiles x 32 n-tiles -> 2 blocks/CU.
__global__ __launch_bounds__(256) void k_gemm(const unsigned short* __restrict__ Abf,
                                              const unsigned short* __restrict__ Bt,
                                              float* __restrict__ Hq,
                                              float* __restrict__ gp) {
  __shared__ unsigned short As[2][2][128 * 32];   // [buf][kk][row*32+col] 32 KB
  __shared__ unsigned short Bs[2][2][64 * 32];    // 16 KB
  __shared__ float red[256];
  const int K = NH;
  int t = threadIdx.x;
  int lane = t & 63;
  int bm = blockIdx.x >> 5, bn = blockIdx.x & 31;
  int wid = t >> 6;
  int wr = wid >> 1, wc = wid & 1;

  // staging: thread t covers 16B granule t of each 4KB chunk.
  // chunk layout inside As[buf][kk]: granule = row*4 + colg; row = t>>2, colg = t&3.
  const unsigned short* AgBase = Abf + (size_t)(bm * 128 + (t >> 2)) * K + (t & 3) * 8;
  const unsigned short* BgBase = Bt  + (size_t)(bn * 64  + (t >> 2)) * K + (t & 3) * 8;

#define STAGE(buf, k0)                                                        \
  do {                                                                        \
    GLOAD_LDS(AgBase + (k0),               &As[buf][0][0] + t * 8);           \
    GLOAD_LDS(AgBase + 64 * K + (k0),      &As[buf][0][0] + 2048 + t * 8);    \
    GLOAD_LDS(AgBase + (k0) + 32,          &As[buf][1][0] + t * 8);           \
    GLOAD_LDS(AgBase + 64 * K + (k0) + 32, &As[buf][1][0] + 2048 + t * 8);    \
    GLOAD_LDS(BgBase + (k0),               &Bs[buf][0][0] + t * 8);           \
    GLOAD_LDS(BgBase + (k0) + 32,          &Bs[buf][1][0] + t * 8);           \
  } while (0)

  f32x4 acc[4][2] = {};

  STAGE(0, 0);
  __syncthreads();                       // drains vmcnt(0): tile 0 resident

  for (int tt = 0; tt < 32; ++tt) {
    int buf = tt & 1;
    if (tt < 31) STAGE(buf ^ 1, (tt + 1) * 64);   // prefetch next tile
#pragma unroll
    for (int kk = 0; kk < 2; ++kk) {
      bf16x8 af[4], bfr[2];
#pragma unroll
      for (int mi = 0; mi < 4; ++mi)
        af[mi] = *(const bf16x8*)&As[buf][kk][(wr * 64 + mi * 16 + (lane & 15)) * 32 + (lane >> 4) * 8];
#pragma unroll
      for (int ni = 0; ni < 2; ++ni)
        bfr[ni] = *(const bf16x8*)&Bs[buf][kk][(wc * 32 + ni * 16 + (lane & 15)) * 32 + (lane >> 4) * 8];
#pragma unroll
      for (int mi = 0; mi < 4; ++mi)
#pragma unroll
        for (int ni = 0; ni < 2; ++ni)
          acc[mi][ni] = __builtin_amdgcn_mfma_f32_16x16x32_bf16(af[mi], bfr[ni], acc[mi][ni], 0, 0, 0);
    }
    __syncthreads();                     // waits prefetch (overlapped) + guards buf reuse
  }
#undef STAGE

  float ss = 0.f;
  int r0 = bm * 128 + wr * 64 + (lane >> 4) * 4;
  int c0 = bn * 64 + wc * 32 + (lane & 15);
#pragma unroll
  for (int mi = 0; mi < 4; ++mi)
#pragma unroll
    for (int r = 0; r < 4; ++r) {
      int row = r0 + mi * 16 + r;
#pragma unroll
      for (int ni = 0; ni < 2; ++ni) {
        float v = acc[mi][ni][r];
        Hq[(size_t)row * NH + c0 + ni * 16] = v;
        ss += v * v;
      }
    }
  float s = blockReduce256(ss, red);
  if (t == 0) gp[blockIdx.x] = s;
}

__global__ void k_scalars(const float* __restrict__ gp, const float* __restrict__ dhp,
                          const float* __restrict__ nrm, float* __restrict__ coef) {
  __shared__ float red[256];
  int t = threadIdx.x;
  float s = blockReduce256(gp[t] + gp[t + 256], red);   // 512 gemm partials
  if (t == 0) {
    float sdh = 0;
    for (int i = 0; i < 8; ++i) sdh += dhp[i];
    float nu  = sqrtf(nrm[0]);
    float nhq = sqrtf(nrm[1] + nrm[2] + 1.0f);
    float ndh = sqrtf(sdh);
    float nHq = sqrtf(s);
    float p1 = sqrtf(nHq / (EPSF + nu));
    float p2 = sqrtf(ndh / (EPSF + nhq));
    coef[0] = C1 * p1;
    coef[1] = C2 * p2;
    coef[2] = C1 / (p1 + EPSF);
    coef[3] = C2 / (p2 + EPSF);
  }
}

// blocks [0,2048): A_next = c1/(p1+eps)*Hq (+ diag) in place.
// blocks [2048,2061): u_next.
__global__ void k_A(float* __restrict__ Hq, const float* __restrict__ dh,
                    const float* __restrict__ coef,
                    const float* __restrict__ u, const float* __restrict__ x,
                    const float* __restrict__ hprev, float* __restrict__ outu) {
  if (blockIdx.x >= 2048) {
    int i = (blockIdx.x - 2048) * 256 + threadIdx.x;
    if (i < NU) {
      float hq = (i < NIN) ? x[i] : (i < NIN + NH ? hprev[i - NIN] : 1.0f);
      outu[i] = coef[0] * u[i] + coef[1] * hq;
    }
    return;
  }
  float sA = coef[2], sD = coef[3];
  size_t i = (size_t)blockIdx.x * 256 + threadIdx.x;
  const size_t stride = (size_t)2048 * 256;             // 2^19
  // 2048 blocks * 256 thr * 8 iters == 2^22 == NH*NH exactly
#pragma unroll
  for (int it = 0; it < 8; ++it, i += stride) {
    float v = sA * Hq[i];
    int row = (int)(i >> 11), col = (int)(i & 2047);
    if (row == col) v += sD * dh[row];
    Hq[i] = v;
  }
}

extern "C" void kernel_launch(void* const* d_in, const int* in_sizes, int n_in,
                              void* d_out, int out_size, void* d_ws, size_t ws_size,
                              hipStream_t stream) {
  const float* x     = (const float*)d_in[0];
  const float* hprev = (const float*)d_in[1];
  const float* Win   = (const float*)d_in[2];
  const float* Wh    = (const float*)d_in[3];
  const float* bias  = (const float*)d_in[4];
  const float* uprev = (const float*)d_in[5];
  const float* Ap    = (const float*)d_in[6];

  float* out  = (float*)d_out;
  float* outh = out;                 // [2048]
  float* outu = out + NH;            // [3073]
  float* Hq   = out + NH + NU;       // [2048*2048] (in-place scaled to A_next)
  float* part = Hq;                  // z-partials borrow Hq region (dead until k_gemm)

  char* ws = (char*)d_ws;
  float* dh   = (float*)ws;
  float* dhp  = (float*)(ws + 8192);
  float* gp   = (float*)(ws + 8256);
  float* nrm  = (float*)(ws + 10304);
  float* coef = (float*)(ws + 10320);
  unsigned short* Abf = (unsigned short*)(ws + 16384);
  unsigned short* Bt  = (unsigned short*)(ws + 8404992);

  k_z1     <<<256,  256, 0, stream>>>(x, hprev, Win, Wh, part);
  k_z2     <<<8,    256, 0, stream>>>(part, bias, outh, dh, dhp);
  k_prep   <<<5121, 256, 0, stream>>>(Wh, dh, Abf, Ap, Bt, uprev, x, hprev, nrm);
  k_gemm   <<<512,  256, 0, stream>>>(Abf, Bt, Hq, gp);
  k_scalars<<<1,    256, 0, stream>>>(gp, dhp, nrm, coef);
  k_A      <<<2061, 256, 0, stream>>>(Hq, dh, coef, uprev, x, hprev, outu);
}

// Round 6
// 72.672 us; speedup vs baseline: 1.1712x; 1.1712x over previous
//
#include <hip/hip_runtime.h>
#include <hip/hip_bf16.h>
#include <math.h>

// signs c1,c2 decoded in round 0/1: both +1 (absmax 0.0078 = bf16 noise)
#define C1 1.0f
#define C2 1.0f

static constexpr float EPSF = 1e-8f;
static constexpr int NIN = 1024;
static constexpr int NH  = 2048;
static constexpr int NU  = NIN + NH + 1;   // 3073

typedef __attribute__((ext_vector_type(8))) short bf16x8;
typedef __attribute__((ext_vector_type(4))) float f32x4;

// ws layout (bytes) -- MUST stay <= 16809984 (round-1 proven ws budget):
//   0       dh    2048 f32 (8 KiB)
//   8192    dhp   8 f32
//   8256    gp    1024 f32 (4 KiB, gemm grid partials)
//   12352   nrm   3 f32
//   16384   Abf   2048*2048 bf16 (8 MiB) = dh[m]*W_h[m][k]
//   8404992 Bt    2048*2048 bf16 (8 MiB) = A_prev^T
//   end 16793600
// z-partials (32*2048 f32, 256 KiB) live in d_out's Hq region (dead until k_gemm).

__device__ inline unsigned short f2bf(float f) {
  union { float f; unsigned u; } v; v.f = f;
  unsigned r = v.u + 0x7FFFu + ((v.u >> 16) & 1u);   // RNE
  return (unsigned short)(r >> 16);
}

__device__ inline float blockReduce256(float v, float* red) {
  int t = threadIdx.x;
  red[t] = v;
  __syncthreads();
  for (int s = 128; s > 0; s >>= 1) {
    if (t < s) red[t] += red[t + s];
    __syncthreads();
  }
  float r = red[0];
  __syncthreads();
  return r;
}

// fused stage 1 (no z-dependency):
//   blocks [0,256)     : z partials (8 j-blocks x 32 i-slices of 96 rows)
//   blocks [256,1280)  : Bt[n][k] = bf16(A_prev[k][n]) 64x64 tiled transpose
//   block  1280        : norms (sumsq u, x, h_prev)
__global__ void k_stage1(const float* __restrict__ x, const float* __restrict__ hprev,
                         const float* __restrict__ Win, const float* __restrict__ Wh,
                         float* __restrict__ part,
                         const float* __restrict__ Ap, unsigned short* __restrict__ Bt,
                         const float* __restrict__ u, float* __restrict__ nrm) {
  __shared__ float ls[64][65];
  int b = blockIdx.x;
  int t = threadIdx.x;
  if (b < 256) {
    int bj = b & 7, bi = b >> 3;
    int j = bj * 256 + t;
    int i0 = bi * 96, i1 = i0 + 96;     // 32*96 == 3072 == NIN+NH exactly
    float s = 0.f;
    for (int i = i0; i < i1; ++i) {
      if (i < NIN) s += x[i] * Win[(size_t)i * NH + j];
      else         s += hprev[i - NIN] * Wh[(size_t)(i - NIN) * NH + j];
    }
    part[bi * NH + j] = s;
  } else if (b < 1280) {
    int bb = b - 256;
    int tn = bb & 31, tk = bb >> 5;
    int r = t >> 4, c = (t & 15) * 4;
#pragma unroll
    for (int i = 0; i < 4; ++i) {
      float4 v = *(const float4*)&Ap[(size_t)(tk * 64 + r + i * 16) * NH + tn * 64 + c];
      ls[r + i * 16][c] = v.x; ls[r + i * 16][c + 1] = v.y;
      ls[r + i * 16][c + 2] = v.z; ls[r + i * 16][c + 3] = v.w;
    }
    __syncthreads();
#pragma unroll
    for (int i = 0; i < 4; ++i) {
      int n = r + i * 16;
      ushort4 o;
      o.x = f2bf(ls[c][n]);     o.y = f2bf(ls[c + 1][n]);
      o.z = f2bf(ls[c + 2][n]); o.w = f2bf(ls[c + 3][n]);
      *(ushort4*)&Bt[(size_t)(tn * 64 + n) * NH + tk * 64 + c] = o;
    }
  } else {
    float* red = (float*)ls;
    float su = 0, sx = 0, sh = 0;
    for (int i = t; i < NU;  i += 256) su += u[i] * u[i];
    for (int i = t; i < NIN; i += 256) sx += x[i] * x[i];
    for (int i = t; i < NH;  i += 256) sh += hprev[i] * hprev[i];
    float r0 = blockReduce256(su, red);
    float r1 = blockReduce256(sx, red);
    float r2 = blockReduce256(sh, red);
    if (t == 0) { nrm[0] = r0; nrm[1] = r1; nrm[2] = r2; }
  }
}

__global__ void k_z2(const float* __restrict__ part, const float* __restrict__ bias,
                     float* __restrict__ outh, float* __restrict__ dh,
                     float* __restrict__ dhp) {
  __shared__ float red[256];
  int j = blockIdx.x * 256 + threadIdx.x;
  float z = bias[j];
  for (int bi = 0; bi < 32; ++bi) z += part[bi * NH + j];
  float h = tanhf(z);
  outh[j] = h;
  float d = 1.f - h * h;
  dh[j] = d;
  float s = blockReduce256(d * d, red);
  if (threadIdx.x == 0) dhp[blockIdx.x] = s;
}

// Abf[m][k] = bf16(dh[m] * W_h[m][k]); 4096*256 float4 == 2^20 == Wh/4 exactly
__global__ void k_prep_a(const float* __restrict__ Wh, const float* __restrict__ dh,
                         unsigned short* __restrict__ Abf) {
  int idx4 = blockIdx.x * 256 + threadIdx.x;
  float4 w = ((const float4*)Wh)[idx4];
  float d = dh[idx4 >> 9];                    // 512 float4 per row
  ushort4 o;
  o.x = f2bf(w.x * d); o.y = f2bf(w.y * d);
  o.z = f2bf(w.z * d); o.w = f2bf(w.w * d);
  ((ushort4*)Abf)[idx4] = o;
}

#define GLOAD_LDS(gsrc, ldst) \
  __builtin_amdgcn_global_load_lds( \
      (const __attribute__((address_space(1))) unsigned int*)(gsrc), \
      (__attribute__((address_space(3))) unsigned int*)(ldst), 16, 0, 0)

// C[m][n] = sum_k Abf[m][k]*Bt[n][k] (= H @ A_prev).
// 64x64 tile, BK=32, 4 waves; wave subtile 32x32 (acc[2][2]).
// Grid 1024 = 32x32 tiles -> 4 blocks/CU (16 waves/CU): barrier stalls of one
// block overlap compute of the other 3 (m114 wave-level overlap).
__global__ __launch_bounds__(256) void k_gemm(const unsigned short* __restrict__ Abf,
                                              const unsigned short* __restrict__ Bt,
                                              float* __restrict__ Hq,
                                              float* __restrict__ gp) {
  __shared__ unsigned short As[64 * 32];
  __shared__ unsigned short Bs[64 * 32];
  __shared__ float red[256];
  const int K = NH;
  int t = threadIdx.x;
  int lane = t & 63;
  int bm = blockIdx.x >> 5, bn = blockIdx.x & 31;
  int wid = t >> 6;
  int wr = wid >> 1, wc = wid & 1;

  const unsigned short* Ag = Abf + (size_t)(bm * 64 + (t >> 2)) * K + (t & 3) * 8;
  const unsigned short* Bg = Bt  + (size_t)(bn * 64 + (t >> 2)) * K + (t & 3) * 8;
  unsigned short* AsT = As + t * 8;   // linear: wave-uniform base + lane*16B
  unsigned short* BsT = Bs + t * 8;

  f32x4 acc[2][2] = {};

  for (int k0 = 0; k0 < K; k0 += 32) {
    GLOAD_LDS(Ag + k0, AsT);
    GLOAD_LDS(Bg + k0, BsT);
    __syncthreads();
    bf16x8 af[2], bfr[2];
#pragma unroll
    for (int mi = 0; mi < 2; ++mi)
      af[mi] = *(const bf16x8*)&As[(wr * 32 + mi * 16 + (lane & 15)) * 32 + (lane >> 4) * 8];
#pragma unroll
    for (int ni = 0; ni < 2; ++ni)
      bfr[ni] = *(const bf16x8*)&Bs[(wc * 32 + ni * 16 + (lane & 15)) * 32 + (lane >> 4) * 8];
#pragma unroll
    for (int mi = 0; mi < 2; ++mi)
#pragma unroll
      for (int ni = 0; ni < 2; ++ni)
        acc[mi][ni] = __builtin_amdgcn_mfma_f32_16x16x32_bf16(af[mi], bfr[ni], acc[mi][ni], 0, 0, 0);
    __syncthreads();
  }

  float ss = 0.f;
  int r0 = bm * 64 + wr * 32 + (lane >> 4) * 4;
  int c0 = bn * 64 + wc * 32 + (lane & 15);
#pragma unroll
  for (int mi = 0; mi < 2; ++mi)
#pragma unroll
    for (int r = 0; r < 4; ++r) {
      int row = r0 + mi * 16 + r;
#pragma unroll
      for (int ni = 0; ni < 2; ++ni) {
        float v = acc[mi][ni][r];
        Hq[(size_t)row * NH + c0 + ni * 16] = v;
        ss += v * v;
      }
    }
  float s = blockReduce256(ss, red);
  if (t == 0) gp[blockIdx.x] = s;
}

// blocks [0,2048): A_next = c1/(p1+eps)*Hq (+ diag) in place.
// blocks [2048,2061): u_next.
// Every block re-reduces the 1024 gemm partials + dhp + nrm and computes coef
// inline (identical fixed-order arithmetic per block -> deterministic; ~4KB L2
// read per block). Kills the separate k_scalars dispatch.
__global__ void k_Au(float* __restrict__ Hq, const float* __restrict__ dh,
                     const float* __restrict__ gp, const float* __restrict__ dhp,
                     const float* __restrict__ nrm,
                     const float* __restrict__ u, const float* __restrict__ x,
                     const float* __restrict__ hprev, float* __restrict__ outu) {
  __shared__ float red[256];
  __shared__ float cf[4];
  int t = threadIdx.x;
  float s = blockReduce256(gp[t] + gp[t + 256] + gp[t + 512] + gp[t + 768], red);
  if (t == 0) {
    float sdh = 0;
    for (int i = 0; i < 8; ++i) sdh += dhp[i];
    float nu  = sqrtf(nrm[0]);
    float nhq = sqrtf(nrm[1] + nrm[2] + 1.0f);
    float ndh = sqrtf(sdh);
    float nHq = sqrtf(s);
    float p1 = sqrtf(nHq / (EPSF + nu));
    float p2 = sqrtf(ndh / (EPSF + nhq));
    cf[0] = C1 * p1;
    cf[1] = C2 * p2;
    cf[2] = C1 / (p1 + EPSF);
    cf[3] = C2 / (p2 + EPSF);
  }
  __syncthreads();

  if (blockIdx.x >= 2048) {
    int i = (blockIdx.x - 2048) * 256 + t;
    if (i < NU) {
      float hq = (i < NIN) ? x[i] : (i < NIN + NH ? hprev[i - NIN] : 1.0f);
      outu[i] = cf[0] * u[i] + cf[1] * hq;
    }
    return;
  }
  float sA = cf[2], sD = cf[3];
  size_t i = (size_t)blockIdx.x * 256 + t;
  const size_t stride = (size_t)2048 * 256;             // 2^19
  // 2048 blocks * 256 thr * 8 iters == 2^22 == NH*NH exactly
#pragma unroll
  for (int it = 0; it < 8; ++it, i += stride) {
    float v = sA * Hq[i];
    int row = (int)(i >> 11), col = (int)(i & 2047);
    if (row == col) v += sD * dh[row];
    Hq[i] = v;
  }
}

extern "C" void kernel_launch(void* const* d_in, const int* in_sizes, int n_in,
                              void* d_out, int out_size, void* d_ws, size_t ws_size,
                              hipStream_t stream) {
  const float* x     = (const float*)d_in[0];
  const float* hprev = (const float*)d_in[1];
  const float* Win   = (const float*)d_in[2];
  const float* Wh    = (const float*)d_in[3];
  const float* bias  = (const float*)d_in[4];
  const float* uprev = (const float*)d_in[5];
  const float* Ap    = (const float*)d_in[6];

  float* out  = (float*)d_out;
  float* outh = out;                 // [2048]
  float* outu = out + NH;            // [3073]
  float* Hq   = out + NH + NU;       // [2048*2048] (in-place scaled to A_next)
  float* part = Hq;                  // z-partials borrow Hq region (dead until k_gemm)

  char* ws = (char*)d_ws;
  float* dh   = (float*)ws;
  float* dhp  = (float*)(ws + 8192);
  float* gp   = (float*)(ws + 8256);
  float* nrm  = (float*)(ws + 12352);
  unsigned short* Abf = (unsigned short*)(ws + 16384);
  unsigned short* Bt  = (unsigned short*)(ws + 8404992);

  k_stage1 <<<1281, 256, 0, stream>>>(x, hprev, Win, Wh, part, Ap, Bt, uprev, nrm);
  k_z2     <<<8,    256, 0, stream>>>(part, bias, outh, dh, dhp);
  k_prep_a <<<4096, 256, 0, stream>>>(Wh, dh, Abf);
  k_gemm   <<<1024, 256, 0, stream>>>(Abf, Bt, Hq, gp);
  k_Au     <<<2061, 256, 0, stream>>>(Hq, dh, gp, dhp, nrm, uprev, x, hprev, outu);
}

// Round 7
// 62.298 us; speedup vs baseline: 1.3662x; 1.1665x over previous
//
#include <hip/hip_runtime.h>
#include <hip/hip_bf16.h>
#include <math.h>

// signs c1,c2 decoded in round 0/1: both +1 (absmax 0.0078 = bf16 noise)
#define C1 1.0f
#define C2 1.0f

static constexpr float EPSF = 1e-8f;
static constexpr int NIN = 1024;
static constexpr int NH  = 2048;
static constexpr int NU  = NIN + NH + 1;   // 3073

typedef __attribute__((ext_vector_type(8))) short bf16x8;
typedef __attribute__((ext_vector_type(4))) float f32x4;

// ws layout (bytes) -- MUST stay <= 16809984 (round-1 proven ws budget):
//   0       dh    2048 f32 (8 KiB)
//   8192    dhp   8 f32
//   8256    gp    1024 f32 (4 KiB, gemm grid partials)
//   12352   nrm   3 f32
//   16384   Abf   2048*2048 bf16 (8 MiB) = dh[m]*W_h[m][k]
//   8404992 Bt    2048*2048 bf16 (8 MiB) = A_prev^T
//   end 16793600
// z-partials (32*2048 f32, 256 KiB) live in d_out's Hq region (dead until k_gemm).

__device__ inline unsigned short f2bf(float f) {
  union { float f; unsigned u; } v; v.f = f;
  unsigned r = v.u + 0x7FFFu + ((v.u >> 16) & 1u);   // RNE
  return (unsigned short)(r >> 16);
}

__device__ inline float blockReduce256(float v, float* red) {
  int t = threadIdx.x;
  red[t] = v;
  __syncthreads();
  for (int s = 128; s > 0; s >>= 1) {
    if (t < s) red[t] += red[t + s];
    __syncthreads();
  }
  float r = red[0];
  __syncthreads();
  return r;
}

// fused stage 1 (no z-dependency):
//   blocks [0,256)     : z partials (8 j-blocks x 32 i-slices of 96 rows)
//   blocks [256,1280)  : Bt[n][k] = bf16(A_prev[k][n]) 64x64 tiled transpose
//   block  1280        : norms (sumsq u, x, h_prev)
__global__ void k_stage1(const float* __restrict__ x, const float* __restrict__ hprev,
                         const float* __restrict__ Win, const float* __restrict__ Wh,
                         float* __restrict__ part,
                         const float* __restrict__ Ap, unsigned short* __restrict__ Bt,
                         const float* __restrict__ u, float* __restrict__ nrm) {
  __shared__ float ls[64][65];
  int b = blockIdx.x;
  int t = threadIdx.x;
  if (b < 256) {
    int bj = b & 7, bi = b >> 3;
    int j = bj * 256 + t;
    int i0 = bi * 96, i1 = i0 + 96;     // 32*96 == 3072 == NIN+NH exactly
    float s = 0.f;
    for (int i = i0; i < i1; ++i) {
      if (i < NIN) s += x[i] * Win[(size_t)i * NH + j];
      else         s += hprev[i - NIN] * Wh[(size_t)(i - NIN) * NH + j];
    }
    part[bi * NH + j] = s;
  } else if (b < 1280) {
    int bb = b - 256;
    int tn = bb & 31, tk = bb >> 5;
    int r = t >> 4, c = (t & 15) * 4;
#pragma unroll
    for (int i = 0; i < 4; ++i) {
      float4 v = *(const float4*)&Ap[(size_t)(tk * 64 + r + i * 16) * NH + tn * 64 + c];
      ls[r + i * 16][c] = v.x; ls[r + i * 16][c + 1] = v.y;
      ls[r + i * 16][c + 2] = v.z; ls[r + i * 16][c + 3] = v.w;
    }
    __syncthreads();
#pragma unroll
    for (int i = 0; i < 4; ++i) {
      int n = r + i * 16;
      ushort4 o;
      o.x = f2bf(ls[c][n]);     o.y = f2bf(ls[c + 1][n]);
      o.z = f2bf(ls[c + 2][n]); o.w = f2bf(ls[c + 3][n]);
      *(ushort4*)&Bt[(size_t)(tn * 64 + n) * NH + tk * 64 + c] = o;
    }
  } else {
    float* red = (float*)ls;
    float su = 0, sx = 0, sh = 0;
    for (int i = t; i < NU;  i += 256) su += u[i] * u[i];
    for (int i = t; i < NIN; i += 256) sx += x[i] * x[i];
    for (int i = t; i < NH;  i += 256) sh += hprev[i] * hprev[i];
    float r0 = blockReduce256(su, red);
    float r1 = blockReduce256(sx, red);
    float r2 = blockReduce256(sh, red);
    if (t == 0) { nrm[0] = r0; nrm[1] = r1; nrm[2] = r2; }
  }
}

// fused: blocks [0,4096): Abf[m][k] = bf16(dh[m]*W_h[m][k]) with dh recomputed
// per block from z-partials (each block covers exactly ONE row m = b>>1);
// blocks [4096,4104): z2 epilogue (h_next, dh array for k_Au diag, dhp sumsq).
__global__ void k_prep(const float* __restrict__ Wh, const float* __restrict__ part,
                       const float* __restrict__ bias,
                       unsigned short* __restrict__ Abf,
                       float* __restrict__ outh, float* __restrict__ dh,
                       float* __restrict__ dhp) {
  __shared__ float red[256];
  __shared__ float dhs;
  int b = blockIdx.x, t = threadIdx.x;
  if (b < 4096) {
    int r = b >> 1;                       // 256 float4 per block = half a 512-float4 row
    if (t < 32) red[t] = part[t * NH + r];
    __syncthreads();
    if (t == 0) {
      float z = bias[r];
      for (int i = 0; i < 32; ++i) z += red[i];
      float h = tanhf(z);
      dhs = 1.f - h * h;
    }
    __syncthreads();
    float d = dhs;
    int idx4 = b * 256 + t;               // 4096*256 == 2^20 == Wh/4 exactly
    float4 w = ((const float4*)Wh)[idx4];
    ushort4 o;
    o.x = f2bf(w.x * d); o.y = f2bf(w.y * d);
    o.z = f2bf(w.z * d); o.w = f2bf(w.w * d);
    ((ushort4*)Abf)[idx4] = o;
  } else {
    int j = (b - 4096) * 256 + t;
    float z = bias[j];
    for (int bi = 0; bi < 32; ++bi) z += part[bi * NH + j];
    float h = tanhf(z);
    outh[j] = h;
    float d = 1.f - h * h;
    dh[j] = d;
    float s = blockReduce256(d * d, red);
    if (t == 0) dhp[b - 4096] = s;
  }
}

#define GLOAD_LDS(gsrc, ldst) \
  __builtin_amdgcn_global_load_lds( \
      (const __attribute__((address_space(1))) unsigned int*)(gsrc), \
      (__attribute__((address_space(3))) unsigned int*)(ldst), 16, 0, 0)

// C[m][n] = sum_k Abf[m][k]*Bt[n][k] (= H @ A_prev).
// 64x64 tile, BK=64, 4 waves; wave subtile 32x32 (acc[2][2]), 8 MFMA/step.
// LDS: k-granule layout [row][kg] (kg = 16B unit), XOR-swizzled kg ^= row&7
// (BK=64 row stride = 128B = full bank wrap -> unswizzled would be 16-way
// conflict; swizzle spreads 16 lanes over 8 bank-slots = 2-way = free).
// Swizzle applied BOTH sides (rule #21): pre-swizzled GLOBAL source address
// (permutation stays inside one 128B line -> coalescing kept) + linear
// global_load_lds dest + XOR'd ds_read address.
// Grid 1024 -> 4 blocks/CU; 32 stage->drain->compute iterations.
__global__ __launch_bounds__(256) void k_gemm(const unsigned short* __restrict__ Abf,
                                              const unsigned short* __restrict__ Bt,
                                              float* __restrict__ Hq,
                                              float* __restrict__ gp) {
  __shared__ unsigned short As[512 * 8];   // 512 granules x 16B = 8KB
  __shared__ unsigned short Bs[512 * 8];
  __shared__ float red[256];
  const int K = NH;
  int t = threadIdx.x;
  int lane = t & 63;
  int bm = blockIdx.x >> 5, bn = blockIdx.x & 31;
  int wid = t >> 6;
  int wr = wid >> 1, wc = wid & 1;

  // staging: thread t owns granules t and t+256; granule g=(row<<3)|kg,
  // physical (row,kg) holds global k-slice (kg ^ (row&7)). row+32 has same row&7.
  int srow = t >> 3, skg = t & 7;
  int sx = skg ^ (srow & 7);
  const unsigned short* AgBase = Abf + (size_t)(bm * 64 + srow) * K + sx * 8;
  const unsigned short* BgBase = Bt  + (size_t)(bn * 64 + srow) * K + sx * 8;

  f32x4 acc[2][2] = {};

  for (int k0 = 0; k0 < K; k0 += 64) {
    GLOAD_LDS(AgBase + k0,          As + t * 8);
    GLOAD_LDS(AgBase + 32 * K + k0, As + (t + 256) * 8);
    GLOAD_LDS(BgBase + k0,          Bs + t * 8);
    GLOAD_LDS(BgBase + 32 * K + k0, Bs + (t + 256) * 8);
    __syncthreads();
    __builtin_amdgcn_s_setprio(1);
#pragma unroll
    for (int kk = 0; kk < 2; ++kk) {
      bf16x8 af[2], bfr[2];
#pragma unroll
      for (int mi = 0; mi < 2; ++mi) {
        int row = wr * 32 + mi * 16 + (lane & 15);
        int kg = (kk * 4 + (lane >> 4)) ^ (row & 7);
        af[mi] = *(const bf16x8*)&As[(row * 8 + kg) * 8];
      }
#pragma unroll
      for (int ni = 0; ni < 2; ++ni) {
        int row = wc * 32 + ni * 16 + (lane & 15);
        int kg = (kk * 4 + (lane >> 4)) ^ (row & 7);
        bfr[ni] = *(const bf16x8*)&Bs[(row * 8 + kg) * 8];
      }
#pragma unroll
      for (int mi = 0; mi < 2; ++mi)
#pragma unroll
        for (int ni = 0; ni < 2; ++ni)
          acc[mi][ni] = __builtin_amdgcn_mfma_f32_16x16x32_bf16(af[mi], bfr[ni], acc[mi][ni], 0, 0, 0);
    }
    __builtin_amdgcn_s_setprio(0);
    __syncthreads();
  }

  float ss = 0.f;
  int r0 = bm * 64 + wr * 32 + (lane >> 4) * 4;
  int c0 = bn * 64 + wc * 32 + (lane & 15);
#pragma unroll
  for (int mi = 0; mi < 2; ++mi)
#pragma unroll
    for (int r = 0; r < 4; ++r) {
      int row = r0 + mi * 16 + r;
#pragma unroll
      for (int ni = 0; ni < 2; ++ni) {
        float v = acc[mi][ni][r];
        Hq[(size_t)row * NH + c0 + ni * 16] = v;
        ss += v * v;
      }
    }
  float s = blockReduce256(ss, red);
  if (t == 0) gp[blockIdx.x] = s;
}

// blocks [0,2048): A_next = c1/(p1+eps)*Hq (+ diag) in place.
// blocks [2048,2061): u_next.
// Every block re-reduces the 1024 gemm partials + dhp + nrm and computes coef
// inline (identical fixed-order arithmetic per block -> deterministic).
__global__ void k_Au(float* __restrict__ Hq, const float* __restrict__ dh,
                     const float* __restrict__ gp, const float* __restrict__ dhp,
                     const float* __restrict__ nrm,
                     const float* __restrict__ u, const float* __restrict__ x,
                     const float* __restrict__ hprev, float* __restrict__ outu) {
  __shared__ float red[256];
  __shared__ float cf[4];
  int t = threadIdx.x;
  float s = blockReduce256(gp[t] + gp[t + 256] + gp[t + 512] + gp[t + 768], red);
  if (t == 0) {
    float sdh = 0;
    for (int i = 0; i < 8; ++i) sdh += dhp[i];
    float nu  = sqrtf(nrm[0]);
    float nhq = sqrtf(nrm[1] + nrm[2] + 1.0f);
    float ndh = sqrtf(sdh);
    float nHq = sqrtf(s);
    float p1 = sqrtf(nHq / (EPSF + nu));
    float p2 = sqrtf(ndh / (EPSF + nhq));
    cf[0] = C1 * p1;
    cf[1] = C2 * p2;
    cf[2] = C1 / (p1 + EPSF);
    cf[3] = C2 / (p2 + EPSF);
  }
  __syncthreads();

  if (blockIdx.x >= 2048) {
    int i = (blockIdx.x - 2048) * 256 + t;
    if (i < NU) {
      float hq = (i < NIN) ? x[i] : (i < NIN + NH ? hprev[i - NIN] : 1.0f);
      outu[i] = cf[0] * u[i] + cf[1] * hq;
    }
    return;
  }
  float sA = cf[2], sD = cf[3];
  size_t i = (size_t)blockIdx.x * 256 + t;
  const size_t stride = (size_t)2048 * 256;             // 2^19
  // 2048 blocks * 256 thr * 8 iters == 2^22 == NH*NH exactly
#pragma unroll
  for (int it = 0; it < 8; ++it, i += stride) {
    float v = sA * Hq[i];
    int row = (int)(i >> 11), col = (int)(i & 2047);
    if (row == col) v += sD * dh[row];
    Hq[i] = v;
  }
}

extern "C" void kernel_launch(void* const* d_in, const int* in_sizes, int n_in,
                              void* d_out, int out_size, void* d_ws, size_t ws_size,
                              hipStream_t stream) {
  const float* x     = (const float*)d_in[0];
  const float* hprev = (const float*)d_in[1];
  const float* Win   = (const float*)d_in[2];
  const float* Wh    = (const float*)d_in[3];
  const float* bias  = (const float*)d_in[4];
  const float* uprev = (const float*)d_in[5];
  const float* Ap    = (const float*)d_in[6];

  float* out  = (float*)d_out;
  float* outh = out;                 // [2048]
  float* outu = out + NH;            // [3073]
  float* Hq   = out + NH + NU;       // [2048*2048] (in-place scaled to A_next)
  float* part = Hq;                  // z-partials borrow Hq region (dead until k_gemm)

  char* ws = (char*)d_ws;
  float* dh   = (float*)ws;
  float* dhp  = (float*)(ws + 8192);
  float* gp   = (float*)(ws + 8256);
  float* nrm  = (float*)(ws + 12352);
  unsigned short* Abf = (unsigned short*)(ws + 16384);
  unsigned short* Bt  = (unsigned short*)(ws + 8404992);

  k_stage1 <<<1281, 256, 0, stream>>>(x, hprev, Win, Wh, part, Ap, Bt, uprev, nrm);
  k_prep   <<<4104, 256, 0, stream>>>(Wh, part, bias, Abf, outh, dh, dhp);
  k_gemm   <<<1024, 256, 0, stream>>>(Abf, Bt, Hq, gp);
  k_Au     <<<2061, 256, 0, stream>>>(Hq, dh, gp, dhp, nrm, uprev, x, hprev, outu);
}